// Round 7
// baseline (2044.487 us; speedup 1.0000x reference)
//
#include <hip/hip_runtime.h>
#include <stdint.h>

#define N_NODES 50000
#define N_EDGES 400000
#define M_PAD   50048   // 391 * 128

typedef __attribute__((ext_vector_type(8))) __bf16 bf16x8;
typedef __attribute__((ext_vector_type(4))) float floatx4;

__device__ __forceinline__ unsigned short f2bf(float f) {
    unsigned int u = __float_as_uint(f);
    unsigned int r = (u + 0x7fffu + ((u >> 16) & 1u)) >> 16;
    return (unsigned short)r;
}

__device__ __forceinline__ void gload_lds16(const void* g, void* l) {
    __builtin_amdgcn_global_load_lds((__attribute__((address_space(1))) void*)g,
                                     (__attribute__((address_space(3))) void*)l,
                                     16, 0, 0);
}

// ---------------- x fp32 -> bf16 (padded to M_PAD rows) ----------------
__global__ void k_conv_x(const float* __restrict__ x, unsigned short* __restrict__ xb) {
    const int total = M_PAD * 256;  // float4 units per row
    for (int u = blockIdx.x * blockDim.x + threadIdx.x; u < total; u += gridDim.x * blockDim.x) {
        int row = u >> 8;
        int c4  = u & 255;
        float4 v = make_float4(0.f, 0.f, 0.f, 0.f);
        if (row < N_NODES) v = ((const float4*)x)[(size_t)row * 256 + c4];
        ushort4 o;
        o.x = f2bf(v.x); o.y = f2bf(v.y); o.z = f2bf(v.z); o.w = f2bf(v.w);
        ((ushort4*)xb)[u] = o;
    }
}

// ---------------- build W^T (bf16, [ncol=1024][k=1024]) + bias concat ----------------
__global__ void k_build_w(const float* __restrict__ Wq, const float* __restrict__ Wk,
                          const float* __restrict__ Wv, const float* __restrict__ Ws,
                          const float* __restrict__ bq, const float* __restrict__ bk,
                          const float* __restrict__ bv, const float* __restrict__ bs,
                          unsigned short* __restrict__ WT, float* __restrict__ biascat) {
    int idx = blockIdx.x * blockDim.x + threadIdx.x;
    if (idx < 1024 * 1024) {
        int n = idx >> 10;        // output col 0..1023
        int k = idx & 1023;       // input dim
        int g = n >> 8, d = n & 255;
        const float* W = (g == 0) ? Wq : (g == 1) ? Wk : (g == 2) ? Wv : Ws;
        WT[idx] = f2bf(W[k * 256 + d]);
    }
    if (idx < 1024) {
        int g = idx >> 8, d = idx & 255;
        const float* B = (g == 0) ? bq : (g == 1) ? bk : (g == 2) ? bv : bs;
        biascat[idx] = B[d];
    }
}

// ---------------- bf16 MFMA GEMM: C[M_PAD][1024] = A[M_PAD][1024] * B[1024][1024] + bias --------
__launch_bounds__(256)
__global__ void k_gemm(const unsigned short* __restrict__ A,
                       const unsigned short* __restrict__ BT,
                       const float* __restrict__ bias,
                       float* __restrict__ Cmat) {
    __shared__ unsigned short As[128 * 32];
    __shared__ unsigned short Bs[128 * 32];
    const int t = threadIdx.x;
    const int w = t >> 6;
    const int l = t & 63;
    const int row0 = blockIdx.y * 128;
    const int col0 = blockIdx.x * 128;

    const int lr = l >> 2;          // row within 16-row wave chunk
    const int lc = (l & 3) * 8;     // bf16-elem offset within row (16B granules)

    const int wr = (w >> 1) * 64;
    const int wc = (w & 1) * 64;
    const int lane15 = l & 15;
    const int quad = l >> 4;

    floatx4 acc[4][4];
#pragma unroll
    for (int i = 0; i < 4; i++)
#pragma unroll
        for (int j = 0; j < 4; j++) acc[i][j] = (floatx4)0.f;

    for (int kk = 0; kk < 1024; kk += 32) {
        __syncthreads();
#pragma unroll
        for (int issue = 0; issue < 2; issue++) {
            int arow = row0 + issue * 64 + w * 16 + lr;
            gload_lds16(A + (size_t)arow * 1024 + kk + lc, As + issue * 2048 + w * 512);
            int brow = col0 + issue * 64 + w * 16 + lr;
            gload_lds16(BT + (size_t)brow * 1024 + kk + lc, Bs + issue * 2048 + w * 512);
        }
        __builtin_amdgcn_s_waitcnt(0x0f70);  // vmcnt(0)
        __syncthreads();

        bf16x8 af[4], bfr[4];
#pragma unroll
        for (int i = 0; i < 4; i++) {
            af[i]  = *(const bf16x8*)(As + (wr + i * 16 + lane15) * 32 + quad * 8);
            bfr[i] = *(const bf16x8*)(Bs + (wc + i * 16 + lane15) * 32 + quad * 8);
        }
#pragma unroll
        for (int i = 0; i < 4; i++)
#pragma unroll
            for (int j = 0; j < 4; j++)
                acc[i][j] = __builtin_amdgcn_mfma_f32_16x16x32_bf16(af[i], bfr[j], acc[i][j], 0, 0, 0);
    }

#pragma unroll
    for (int i = 0; i < 4; i++) {
#pragma unroll
        for (int j = 0; j < 4; j++) {
            int col = col0 + wc + j * 16 + lane15;
            float bcol = bias[col];
#pragma unroll
            for (int r = 0; r < 4; r++) {
                int row = row0 + wr + i * 16 + quad * 4 + r;
                Cmat[(size_t)row * 1024 + col] = acc[i][j][r] + bcol;
            }
        }
    }
}

// ---------------- edge pass 1: s = q[dst].k[src]/8, ex=exp(s), den[dst,h]+=ex ----------------
__global__ void k_edge1(const int* __restrict__ ei, const float* __restrict__ qkvs,
                        float* __restrict__ exbuf, float* __restrict__ den) {
    int w = threadIdx.x >> 6, l = threadIdx.x & 63;
    int e = blockIdx.x * 4 + w;
    if (e >= N_EDGES) return;
    int src = ei[e];
    int dst = ei[N_EDGES + e];
    const float4* qrow = (const float4*)(qkvs + (size_t)dst * 1024);
    const float4* krow = (const float4*)(qkvs + (size_t)src * 1024 + 256);
    float4 qv = qrow[l], kv = krow[l];
    float p = qv.x * kv.x + qv.y * kv.y + qv.z * kv.z + qv.w * kv.w;
    p += __shfl_xor(p, 1, 16);
    p += __shfl_xor(p, 2, 16);
    p += __shfl_xor(p, 4, 16);
    p += __shfl_xor(p, 8, 16);
    if ((l & 15) == 0) {
        int hh = l >> 4;
        float ex = expf(p * 0.125f);
        exbuf[(size_t)e * 4 + hh] = ex;
        atomicAdd(&den[dst * 4 + hh], ex);
    }
}

// ---------------- edge pass 2: skip-slot[dst] += (ex/den)*v[src] ----------------
__global__ void k_edge2(const int* __restrict__ ei, float* __restrict__ qkvs,
                        const float* __restrict__ exbuf, const float* __restrict__ den) {
    int w = threadIdx.x >> 6, l = threadIdx.x & 63;
    int e = blockIdx.x * 4 + w;
    if (e >= N_EDGES) return;
    int src = ei[e];
    int dst = ei[N_EDGES + e];
    int hh = l >> 4;
    float alpha = exbuf[(size_t)e * 4 + hh] / den[dst * 4 + hh];
    const float4* vrow = (const float4*)(qkvs + (size_t)src * 1024 + 512);
    float4 vv = vrow[l];
    float* aggp = qkvs + (size_t)dst * 1024 + 768 + l * 4;
    atomicAdd(aggp + 0, alpha * vv.x);
    atomicAdd(aggp + 1, alpha * vv.y);
    atomicAdd(aggp + 2, alpha * vv.z);
    atomicAdd(aggp + 3, alpha * vv.w);
}

// ---------------- h = gelu(agg+skip); write fp32 h to d_out; scores -> exp ----------------
__global__ void k_h(const float* __restrict__ qkvs,
                    const float* __restrict__ gate_w, const float* __restrict__ gate_b,
                    float* __restrict__ out_h, float* __restrict__ exsc) {
    int w = threadIdx.x >> 6, l = threadIdx.x & 63;
    int n = blockIdx.x * 4 + w;
    if (n >= N_NODES) return;
    float4 z = ((const float4*)(qkvs + (size_t)n * 1024 + 768))[l];
    const float is2 = 0.70710678118f;
    float h0 = 0.5f * z.x * (1.f + erff(z.x * is2));
    float h1 = 0.5f * z.y * (1.f + erff(z.y * is2));
    float h2 = 0.5f * z.z * (1.f + erff(z.z * is2));
    float h3 = 0.5f * z.w * (1.f + erff(z.w * is2));
    ((float4*)(out_h + (size_t)n * 256))[l] = make_float4(h0, h1, h2, h3);
    int d0 = l * 4;
    float s0 = h0 * gate_w[(d0 + 0) * 2] + h1 * gate_w[(d0 + 1) * 2] +
               h2 * gate_w[(d0 + 2) * 2] + h3 * gate_w[(d0 + 3) * 2];
    float s1 = h0 * gate_w[(d0 + 0) * 2 + 1] + h1 * gate_w[(d0 + 1) * 2 + 1] +
               h2 * gate_w[(d0 + 2) * 2 + 1] + h3 * gate_w[(d0 + 3) * 2 + 1];
#pragma unroll
    for (int off = 1; off < 64; off <<= 1) {
        s0 += __shfl_xor(s0, off, 64);
        s1 += __shfl_xor(s1, off, 64);
    }
    if (l == 0) {
        exsc[n * 2 + 0] = expf(s0 + gate_b[0]);
        exsc[n * 2 + 1] = expf(s1 + gate_b[1]);
    }
}

// ---------------- esum[c] = sum_n exsc[n,c] ----------------
__global__ void k_esum(const float* __restrict__ exsc, float* __restrict__ esum) {
    __shared__ float red0[4], red1[4];
    float p0 = 0.f, p1 = 0.f;
    for (int n = blockIdx.x * blockDim.x + threadIdx.x; n < N_NODES; n += gridDim.x * blockDim.x) {
        p0 += exsc[n * 2];
        p1 += exsc[n * 2 + 1];
    }
#pragma unroll
    for (int off = 1; off < 64; off <<= 1) {
        p0 += __shfl_xor(p0, off, 64);
        p1 += __shfl_xor(p1, off, 64);
    }
    int w = threadIdx.x >> 6, l = threadIdx.x & 63;
    if (l == 0) { red0[w] = p0; red1[w] = p1; }
    __syncthreads();
    if (threadIdx.x == 0) {
        atomicAdd(&esum[0], red0[0] + red0[1] + red0[2] + red0[3]);
        atomicAdd(&esum[1], red1[0] + red1[1] + red1[2] + red1[3]);
    }
}

// ---------------- attn/A outputs (fp32) + t[c,d] = sum_n attn[n,c] h[n,d] ----------------
__global__ void k_t(const float* __restrict__ exsc, const float* __restrict__ esum,
                    const float* __restrict__ h_f, const int* __restrict__ label_p,
                    float* __restrict__ attn_out, float* __restrict__ A_out,
                    float* __restrict__ t_ws) {
    int d = threadIdx.x;
    float inv0 = 1.f / esum[0], inv1 = 1.f / esum[1];
    int lab = *label_p;
    int n0 = blockIdx.x * 98;
    int n1 = n0 + 98; if (n1 > N_NODES) n1 = N_NODES;
    float t0 = 0.f, t1 = 0.f;
    for (int n = n0; n < n1; n++) {
        float e0 = exsc[n * 2], e1 = exsc[n * 2 + 1];
        float a0 = e0 * inv0, a1 = e1 * inv1;
        float hv = h_f[(size_t)n * 256 + d];
        t0 += a0 * hv;
        t1 += a1 * hv;
        if (d == 0) attn_out[n * 2] = a0;
        else if (d == 1) attn_out[n * 2 + 1] = a1;
        else if (d == 2) A_out[n] = (lab == 0) ? a0 : a1;
    }
    atomicAdd(&t_ws[d], t0);
    atomicAdd(&t_ws[256 + d], t1);
}

// ---------------- y = t @ pool_w + pool_b (fp32 out) ----------------
__global__ void k_y(const float* __restrict__ t_ws, const float* __restrict__ pool_w,
                    const float* __restrict__ pool_b, float* __restrict__ y_out) {
    int d = threadIdx.x;
    float a0 = pool_b[d], a1 = pool_b[d];
    for (int k = 0; k < 256; k++) {
        float w = pool_w[k * 256 + d];
        a0 += t_ws[k] * w;
        a1 += t_ws[256 + k] * w;
    }
    y_out[d] = a0;
    y_out[256 + d] = a1;
}

extern "C" void kernel_launch(void* const* d_in, const int* in_sizes, int n_in,
                              void* d_out, int out_size, void* d_ws, size_t ws_size,
                              hipStream_t stream) {
    const float* x      = (const float*)d_in[0];
    const int*   ei     = (const int*)d_in[1];
    const int*   label  = (const int*)d_in[2];
    const float* Wq     = (const float*)d_in[3];
    const float* bq     = (const float*)d_in[4];
    const float* Wk     = (const float*)d_in[5];
    const float* bk     = (const float*)d_in[6];
    const float* Wv     = (const float*)d_in[7];
    const float* bv     = (const float*)d_in[8];
    const float* Wskip  = (const float*)d_in[9];
    const float* bskip  = (const float*)d_in[10];
    const float* gate_w = (const float*)d_in[11];
    const float* gate_b = (const float*)d_in[12];
    const float* pool_w = (const float*)d_in[13];
    const float* pool_b = (const float*)d_in[14];

    char* ws = (char*)d_ws;
    size_t off = 0;
    float* qkvs = (float*)(ws + off);                 off += (size_t)M_PAD * 1024 * 4;   // 205.0 MB
    unsigned short* xb = (unsigned short*)(ws + off); off += (size_t)M_PAD * 1024 * 2;   // 102.5 MB
    unsigned short* WT = (unsigned short*)(ws + off); off += (size_t)1024 * 1024 * 2;    // 2 MB
    float* biascat = (float*)(ws + off);              off += 1024 * 4;
    float* exbuf = (float*)(ws + off);                off += (size_t)N_EDGES * 4 * 4;    // 6.4 MB
    float* den = (float*)(ws + off);                  off += (size_t)N_NODES * 4 * 4;    // 0.8 MB
    float* exsc = (float*)(ws + off);                 off += (size_t)N_NODES * 2 * 4;    // 0.4 MB
    float* esum = (float*)(ws + off);                 off += 2 * 4;
    float* t_ws = (float*)(ws + off);                 off += 512 * 4;

    // Outputs are FP32, concatenated flat in return order.
    float* out = (float*)d_out;
    float* y_out    = out;                 // 512
    float* attn_out = out + 512;           // 100000
    float* h_out    = out + 100512;        // 12800000
    float* A_out    = out + 12900512;      // 50000

    // zero den + exsc + esum + t_ws (contiguous)
    hipMemsetAsync(den, 0, ((size_t)N_NODES * 4 + N_NODES * 2 + 2 + 512) * 4, stream);

    k_conv_x<<<4096, 256, 0, stream>>>(x, xb);
    k_build_w<<<4096, 256, 0, stream>>>(Wq, Wk, Wv, Wskip, bq, bk, bv, bskip, WT, biascat);
    dim3 ggrid(8, 391);
    k_gemm<<<ggrid, 256, 0, stream>>>(xb, WT, biascat, qkvs);
    k_edge1<<<100000, 256, 0, stream>>>(ei, qkvs, exbuf, den);
    k_edge2<<<100000, 256, 0, stream>>>(ei, qkvs, exbuf, den);
    k_h<<<12500, 256, 0, stream>>>(qkvs, gate_w, gate_b, h_out, exsc);
    k_esum<<<128, 256, 0, stream>>>(exsc, esum);
    k_t<<<512, 256, 0, stream>>>(exsc, esum, h_out, label, attn_out, A_out, t_ws);
    k_y<<<1, 256, 0, stream>>>(t_ws, pool_w, pool_b, y_out);
}